// Round 6
// baseline (201.424 us; speedup 1.0000x reference)
//
#include <hip/hip_runtime.h>
#include <math.h>

// Problem constants
#define B_  4
#define N_  170
#define T_  96
#define D_  256
#define H_  8
#define HD_ 32
#define R_  (B_*N_*T_)    // 65280 rows
#define G_  (B_*N_*H_)    // 5440 attention groups
#define GSZ (T_*HD_)      // 3072 elements per group per tensor
#define QSZ (R_*D_)       // 16,711,680 elements per q/k/v buffer (bf16)
#define WSZ (D_*D_)       // 65536 per weight matrix

typedef short  bf16x8 __attribute__((ext_vector_type(8)));
typedef float  f32x4  __attribute__((ext_vector_type(4)));
typedef unsigned int u32;

#define WAITV8   asm volatile("s_waitcnt vmcnt(8)" ::: "memory")
#define WAITV4   asm volatile("s_waitcnt vmcnt(4)" ::: "memory")
#define WAITV0   asm volatile("s_waitcnt vmcnt(0)" ::: "memory")
#define WAITLGKM asm volatile("s_waitcnt lgkmcnt(0)" ::: "memory")
#define SCHEDB   __builtin_amdgcn_sched_barrier(0)

__device__ __forceinline__ ushort to_bf16(float x)
{
    uint u = __builtin_bit_cast(uint, x);
    u += 0x8000u;                      // round-half-up
    return (ushort)(u >> 16);
}

__device__ __forceinline__ uint pack2(float x0, float x1)
{
    return (uint)to_bf16(x0) | ((uint)to_bf16(x1) << 16);
}

__device__ __forceinline__ uint4 pack8(float4 a0, float4 a1)
{
    uint4 r;
    r.x = pack2(a0.x, a0.y); r.y = pack2(a0.z, a0.w);
    r.z = pack2(a1.x, a1.y); r.w = pack2(a1.z, a1.w);
    return r;
}

// split fp32 pair into packed bf16 hi (truncate; x-hi exact) and lo words
__device__ __forceinline__ void split2(float x0, float x1, uint& hi, uint& lo)
{
    uint u0 = __builtin_bit_cast(uint, x0);
    uint u1 = __builtin_bit_cast(uint, x1);
    hi = (u0 >> 16) | (u1 & 0xFFFF0000u);
    float h0 = __builtin_bit_cast(float, u0 & 0xFFFF0000u);
    float h1 = __builtin_bit_cast(float, u1 & 0xFFFF0000u);
    float l0 = x0 - h0, l1 = x1 - h1;
    uint v0 = __builtin_bit_cast(uint, l0);
    uint v1 = __builtin_bit_cast(uint, l1);
    lo = (v0 >> 16) | (v1 & 0xFFFF0000u);
}

__device__ __forceinline__ void split8(float4 a0, float4 a1, uint4& hi, uint4& lo)
{
    split2(a0.x, a0.y, hi.x, lo.x);
    split2(a0.z, a0.w, hi.y, lo.y);
    split2(a1.x, a1.y, hi.z, lo.z);
    split2(a1.z, a1.w, hi.w, lo.w);
}

// async global->LDS, 16B per lane; lds dest = wave-uniform base + lane*16 (HW)
__device__ __forceinline__ void async_load16(const void* g, void* l)
{
    __builtin_amdgcn_global_load_lds(
        (const u32 __attribute__((address_space(1)))*)g,
        (u32 __attribute__((address_space(3)))*)l,
        16, 0, 0);
}

// ---------------------------------------------------------------------------
// Kernel 0: one-time W split. W[col][k] fp32 -> hi/lo bf16 in chunked layout
// [k/8][col][8] per matrix.  Wq gets 1/sqrt(32) folded in. 0=Wq 1=Wk 2=Wv 3=Wo.
// ---------------------------------------------------------------------------
__global__ __launch_bounds__(256)
void splitw_kernel(const float* __restrict__ Wq, const float* __restrict__ Wk,
                   const float* __restrict__ Wv, const float* __restrict__ Wo,
                   ushort* __restrict__ whi, ushort* __restrict__ wlo)
{
    const int gid = blockIdx.x * 256 + threadIdx.x;   // 32768 chunks
    const int mat = gid >> 13;
    const int rem = gid & 8191;
    const int col = rem >> 5;
    const int kc  = rem & 31;
    const float* W = (mat == 0) ? Wq : (mat == 1) ? Wk : (mat == 2) ? Wv : Wo;
    const float s  = (mat == 0) ? 0.17677669529663687f : 1.0f;
    const float* p = W + (size_t)col * D_ + kc * 8;
    float4 a0 = *(const float4*)p;
    float4 a1 = *(const float4*)(p + 4);
    a0.x *= s; a0.y *= s; a0.z *= s; a0.w *= s;
    a1.x *= s; a1.y *= s; a1.z *= s; a1.w *= s;
    uint4 h, l;
    split8(a0, a1, h, l);
    const size_t off = (size_t)mat * WSZ + ((size_t)kc * 256 + col) * 8;
    *(uint4*)(whi + off) = h;
    *(uint4*)(wlo + off) = l;
}

// ---------------------------------------------------------------------------
// Kernel 1: fused Q/K/V projection, counted-vmcnt 2-phase pipeline.
// A (X, HBM): depth-2 register prefetch (sA0/sA1 ping-pong), pack->LDS.
// B (W hi/lo, L2-hot): depth-1 global_load_lds double buffer.
// Per-step VMEM order: [A(t+1)(4) | B(t+1)(4) | A(t+2)(4)]; compiler auto-waits
// vmcnt(8) for A-pack; manual vmcnt(4) retires B before RAW s_barrier, leaving
// A(t+2) in flight across it.  BM=128, BN=128, BK=32, 4 waves, 64x64/wave.
// ---------------------------------------------------------------------------
__global__ __launch_bounds__(256)
void proj_kernel(const float* __restrict__ Xq, const float* __restrict__ Xk,
                 const float* __restrict__ Xv,
                 const ushort* __restrict__ whi, const ushort* __restrict__ wlo,
                 const float* __restrict__ bq, const float* __restrict__ bk,
                 const float* __restrict__ bv,
                 ushort* __restrict__ oq, ushort* __restrict__ ok_,
                 ushort* __restrict__ ov)
{
    const int z = blockIdx.z;
    const float* X    = (z == 0) ? Xq : (z == 1) ? Xk : Xv;
    const float* bias = (z == 0) ? bq : (z == 1) ? bk : bv;
    ushort*      out  = (z == 0) ? oq : (z == 1) ? ok_ : ov;
    const ushort* Wh = whi + (size_t)z * WSZ;
    const ushort* Wl = wlo + (size_t)z * WSZ;

    const int tid  = threadIdx.x;
    const int lane = tid & 63;
    const int w    = tid >> 6;
    const int col0 = blockIdx.x * 128;
    const int row0 = blockIdx.y * 128;
    const int wr   = w >> 1;
    const int wc   = w & 1;
    const int lr   = lane & 15;
    const int kgl  = lane >> 4;

    __shared__ __align__(16) char Alds[2][8320];    // 4 planes x 130 chunks
    __shared__ __align__(16) char Blds[2][16640];   // 8 planes (hi:0-3, lo:4-7)

    // A stage descriptors: 2 chunks/thread (chunk = 8 bf16 = 16B)
    const int cA1 = tid + 256;
    const int kA0 = tid >> 7, rA0 = tid & 127;
    const int kA1 = cA1 >> 7, rA1 = cA1 & 127;
    const float* pa0 = X + (size_t)(row0 + rA0) * D_ + kA0 * 8;
    const float* pa1 = X + (size_t)(row0 + rA1) * D_ + kA1 * 8;
    const uint wa0 = (uint)(kA0 * 130 + rA0) * 16;
    const uint wa1 = (uint)(kA1 * 130 + rA1) * 16;

    // B stage descriptors: 4 gl_lds issues/wave (64-chunk linear segments)
    const ushort* pb[4];
    uint wb[4];
    #pragma unroll
    for (int i = 0; i < 4; i++) {
        const int s = w * 4 + i, hl = s >> 3, kg = (s >> 1) & 3, colh = s & 1;
        pb[i] = (hl ? Wl : Wh) + ((size_t)kg * 256 + col0 + colh * 64 + lane) * 8;
        wb[i] = (uint)__builtin_amdgcn_readfirstlane(
                    (((hl * 4 + kg) * 130) + colh * 64) * 16);
    }

    f32x4 acc[4][4];
    #pragma unroll
    for (int m = 0; m < 4; m++)
        #pragma unroll
        for (int n = 0; n < 4; n++) acc[m][n] = (f32x4)0.f;

    float4 sA0[4], sA1[4];   // two in-flight A register sets (static-indexed)

#define LOADA(t, S)  do { \
        const float* q0_ = pa0 + (t) * 32; \
        const float* q1_ = pa1 + (t) * 32; \
        S[0] = *(const float4*)q0_;  S[1] = *(const float4*)(q0_ + 4); \
        S[2] = *(const float4*)q1_;  S[3] = *(const float4*)(q1_ + 4); \
    } while (0)
#define WRITEA(buf, S) do { \
        *(uint4*)(Alds[buf] + wa0) = pack8(S[0], S[1]); \
        *(uint4*)(Alds[buf] + wa1) = pack8(S[2], S[3]); \
    } while (0)
#define ISSUEB(t, buf) do { \
        _Pragma("unroll") \
        for (int i_ = 0; i_ < 4; i_++) \
            async_load16(pb[i_] + (size_t)(t) * 8192, Blds[buf] + wb[i_]); \
    } while (0)

    // ---- prologue: A[0]->sA0, B[0]->buf0, A[1]->sA1; write A[0]; barrier ----
    LOADA(0, sA0);  SCHEDB;
    ISSUEB(0, 0);   SCHEDB;
    LOADA(1, sA1);  SCHEDB;
    WRITEA(0, sA0);            // compiler auto-waits vmcnt for sA0 here
    WAITLGKM;
    WAITV4;                    // retire B[0]; leave A[1] in flight
    SCHEDB;
    __builtin_amdgcn_s_barrier();
    SCHEDB;

    #pragma unroll
    for (int t = 0; t < 8; t++) {
        const int cur = t & 1, nxt = cur ^ 1;
        if (t < 7) { ISSUEB(t + 1, nxt); SCHEDB; }
        if (t < 6) {
            if (t & 1) LOADA(t + 2, sA1); else LOADA(t + 2, sA0);
            SCHEDB;
        }
        // ---- compute current tile ----
        {
            bf16x8 a[4];
            #pragma unroll
            for (int m = 0; m < 4; m++)
                a[m] = *(const bf16x8*)(Alds[cur] + (kgl*130 + wr*64 + m*16 + lr) * 16);
            #pragma unroll
            for (int n = 0; n < 4; n++) {
                const int cb = wc*64 + n*16 + lr;
                bf16x8 bh = *(const bf16x8*)(Blds[cur] + (kgl*130 + cb) * 16);
                bf16x8 bl = *(const bf16x8*)(Blds[cur] + ((4 + kgl)*130 + cb) * 16);
                #pragma unroll
                for (int m = 0; m < 4; m++) {
                    acc[m][n] = __builtin_amdgcn_mfma_f32_16x16x32_bf16(a[m], bl, acc[m][n], 0, 0, 0);
                    acc[m][n] = __builtin_amdgcn_mfma_f32_16x16x32_bf16(a[m], bh, acc[m][n], 0, 0, 0);
                }
            }
        }
        if (t < 7) {
            // pack A[t+1] (auto vmcnt(8) retires its loads) and stage to nxt
            if (t & 1) WRITEA(nxt, sA0); else WRITEA(nxt, sA1);
            WAITLGKM;
            if (t < 6) { WAITV4; }   // retire B[t+1]; A[t+2] stays in flight
            else       { WAITV0; }   // t==6: retire B[7] (no A[8])
            SCHEDB;
            __builtin_amdgcn_s_barrier();
            SCHEDB;
        }
    }
#undef LOADA
#undef WRITEA
#undef ISSUEB

    // epilogue: + bias -> bf16, head-split store (Wq pre-scaled; bias scaled here)
    const float sc = (z == 0) ? 0.17677669529663687f : 1.0f;
    if (z < 2) {
        #pragma unroll
        for (int n = 0; n < 4; n++) {
            const int gcol = col0 + wc*64 + n*16 + lr;
            const int h    = gcol >> 5;
            const int hd   = gcol & 31;
            const float bvs = bias[gcol] * sc;
            #pragma unroll
            for (int m = 0; m < 4; m++) {
                #pragma unroll
                for (int reg = 0; reg < 4; reg++) {
                    const int grow = row0 + wr*64 + m*16 + kgl*4 + reg;
                    const int bn = grow / T_;
                    const int t  = grow - bn * T_;
                    out[(size_t)((bn*H_ + h)*T_ + t)*HD_ + hd] = to_bf16(acc[m][n][reg] + bvs);
                }
            }
        }
    } else {
        // v: [g][hd][t], pack 4 consecutive t (reg dim) into ushort4
        #pragma unroll
        for (int n = 0; n < 4; n++) {
            const int gcol = col0 + wc*64 + n*16 + lr;
            const int h    = gcol >> 5;
            const int hd   = gcol & 31;
            const float bvs = bias[gcol];
            #pragma unroll
            for (int m = 0; m < 4; m++) {
                const int grow0 = row0 + wr*64 + m*16 + kgl*4;  // 4 | 96 -> one bn
                const int bn = grow0 / T_;
                const int t0 = grow0 - bn * T_;
                ushort4 pk;
                pk.x = to_bf16(acc[m][n][0] + bvs);
                pk.y = to_bf16(acc[m][n][1] + bvs);
                pk.z = to_bf16(acc[m][n][2] + bvs);
                pk.w = to_bf16(acc[m][n][3] + bvs);
                *(ushort4*)&out[(size_t)((bn*H_ + h)*HD_ + hd)*T_ + t0] = pk;
            }
        }
    }
}

// ---------------------------------------------------------------------------
// Kernel 2: MFMA attention, one block per (bn,h), 384 thr = 6 waves.
// O written as SINGLE bf16 row-major [bn*96+t][h*32+hd] for wo_kernel.
// ---------------------------------------------------------------------------
__global__ __launch_bounds__(384)
void attn_kernel(const ushort* __restrict__ q, const ushort* __restrict__ k,
                 const ushort* __restrict__ vt, ushort* __restrict__ Obf)
{
    const int g   = blockIdx.x;
    const int tid = threadIdx.x;
    __shared__ __align__(16) char lds[37888];

    {
        const ushort* Qg = q  + (size_t)g * GSZ;
        const ushort* Kg = k  + (size_t)g * GSZ;
        const ushort* Vg = vt + (size_t)g * GSZ;
        const int t  = tid >> 2, kg = tid & 3;
        uint4 aq = *(const uint4*)(Qg + tid * 8);
        *(uint4*)(lds + kg*1568 + t*16) = aq;
        uint4 ak = *(const uint4*)(Kg + tid * 8);
        *(uint4*)(lds + 6272 + kg*1568 + t*16) = ak;
        const int hd = tid / 12, pl = tid - hd*12;
        uint4 av = *(const uint4*)(Vg + tid * 8);
        *(uint4*)(lds + 12544 + pl*544 + hd*16) = av;
    }
    __syncthreads();

    const int w = tid >> 6, lane = tid & 63;
    const int lr = lane & 15, kgl = lane >> 4;

    f32x4 acc[6];
    {
        bf16x8 aq = *(const bf16x8*)(lds + kgl*1568 + (w*16 + lr)*16);
        #pragma unroll
        for (int n = 0; n < 6; n++) {
            bf16x8 bk = *(const bf16x8*)(lds + 6272 + kgl*1568 + (n*16 + lr)*16);
            acc[n] = __builtin_amdgcn_mfma_f32_16x16x32_bf16(aq, bk, (f32x4)0.f, 0, 0, 0);
        }
    }

    float mx[4], sm[4], inv[4];
    #pragma unroll
    for (int reg = 0; reg < 4; reg++) {
        float m = acc[0][reg];
        #pragma unroll
        for (int n = 1; n < 6; n++) m = fmaxf(m, acc[n][reg]);
        mx[reg] = m;
    }
    #pragma unroll
    for (int off = 1; off < 16; off <<= 1)
        #pragma unroll
        for (int reg = 0; reg < 4; reg++)
            mx[reg] = fmaxf(mx[reg], __shfl_xor(mx[reg], off));
    #pragma unroll
    for (int reg = 0; reg < 4; reg++) sm[reg] = 0.f;
    #pragma unroll
    for (int n = 0; n < 6; n++)
        #pragma unroll
        for (int reg = 0; reg < 4; reg++) {
            float e = __expf(acc[n][reg] - mx[reg]);
            acc[n][reg] = e;
            sm[reg] += e;
        }
    #pragma unroll
    for (int off = 1; off < 16; off <<= 1)
        #pragma unroll
        for (int reg = 0; reg < 4; reg++)
            sm[reg] += __shfl_xor(sm[reg], off);
    #pragma unroll
    for (int reg = 0; reg < 4; reg++) inv[reg] = 1.0f / sm[reg];

    #pragma unroll
    for (int n = 0; n < 6; n++) {
        const int pl = (n >> 1)*4 + ((n*2 + (lr >> 3)) & 3);
        const int j  = lr & 7;
        #pragma unroll
        for (int reg = 0; reg < 4; reg++) {
            const int row = w*16 + kgl*4 + reg;
            *(ushort*)(lds + 19072 + pl*1568 + row*16 + j*2) =
                to_bf16(acc[n][reg] * inv[reg]);
        }
    }
    __syncthreads();

    f32x4 o[2] = {(f32x4)0.f, (f32x4)0.f};
    #pragma unroll
    for (int ks = 0; ks < 3; ks++) {
        bf16x8 ap = *(const bf16x8*)(lds + 19072 + (ks*4 + kgl)*1568 + (w*16 + lr)*16);
        #pragma unroll
        for (int n2 = 0; n2 < 2; n2++) {
            bf16x8 bv = *(const bf16x8*)(lds + 12544 + (ks*4 + kgl)*544 + (n2*16 + lr)*16);
            o[n2] = __builtin_amdgcn_mfma_f32_16x16x32_bf16(ap, bv, o[n2], 0, 0, 0);
        }
    }

    const int bn = g >> 3, h = g & 7;
    const size_t rb = (size_t)(bn * T_) * D_ + h * HD_;
    #pragma unroll
    for (int n2 = 0; n2 < 2; n2++)
        #pragma unroll
        for (int reg = 0; reg < 4; reg++) {
            const int qr = w*16 + kgl*4 + reg;
            Obf[rb + (size_t)qr * D_ + n2*16 + lr] = to_bf16(o[n2][reg]);
        }
}

// ---------------------------------------------------------------------------
// Kernel 3: d_out = O @ Wo^T + bo. A (O bf16) and B (Wo hi/lo) both via
// global_load_lds, 2-phase double-buffered loop.
// BM=128, BN=128, BK=32, 256 thr = 4 waves.
// ---------------------------------------------------------------------------
__global__ __launch_bounds__(256)
void wo_kernel(const ushort* __restrict__ Obf,
               const ushort* __restrict__ whi, const ushort* __restrict__ wlo,
               const float* __restrict__ bo, float* __restrict__ io)
{
    const int tid  = threadIdx.x;
    const int lane = tid & 63;
    const int w    = tid >> 6;
    const int col0 = blockIdx.x * 128;
    const int row0 = blockIdx.y * 128;
    const int wr   = w >> 1;
    const int wc   = w & 1;
    const int lr   = lane & 15;
    const int kgl  = lane >> 4;
    const ushort* Wh = whi + (size_t)3 * WSZ;
    const ushort* Wl = wlo + (size_t)3 * WSZ;

    __shared__ __align__(16) char Alds[2][8320];
    __shared__ __align__(16) char Blds[2][16640];

    // A: 2 gl_lds issues/wave (s = w*2+i: kg = s>>1, rhalf = s&1)
    const ushort* pa[2];
    uint wa[2];
    #pragma unroll
    for (int i = 0; i < 2; i++) {
        const int s = w * 2 + i, kg = s >> 1, rhalf = s & 1;
        pa[i] = Obf + (size_t)(row0 + rhalf * 64 + lane) * D_ + kg * 8;
        wa[i] = (uint)__builtin_amdgcn_readfirstlane((kg * 130 + rhalf * 64) * 16);
    }
    // B: 4 gl_lds issues/wave
    const ushort* pb[4];
    uint wb[4];
    #pragma unroll
    for (int i = 0; i < 4; i++) {
        const int s = w * 4 + i, hl = s >> 3, kg = (s >> 1) & 3, colh = s & 1;
        pb[i] = (hl ? Wl : Wh) + ((size_t)kg * 256 + col0 + colh * 64 + lane) * 8;
        wb[i] = (uint)__builtin_amdgcn_readfirstlane(
                    (((hl * 4 + kg) * 130) + colh * 64) * 16);
    }

    f32x4 acc[4][4];
    #pragma unroll
    for (int m = 0; m < 4; m++)
        #pragma unroll
        for (int n = 0; n < 4; n++) acc[m][n] = (f32x4)0.f;

    // prologue
    #pragma unroll
    for (int i = 0; i < 2; i++) async_load16(pa[i], Alds[0] + wa[i]);
    #pragma unroll
    for (int i = 0; i < 4; i++) async_load16(pb[i], Blds[0] + wb[i]);
    __syncthreads();

    for (int t = 0; t < 8; t++) {
        const int cur = t & 1, nxt = cur ^ 1;
        if (t < 7) {
            #pragma unroll
            for (int i = 0; i < 2; i++)
                async_load16(pa[i] + (size_t)(t + 1) * 32, Alds[nxt] + wa[i]);
            #pragma unroll
            for (int i = 0; i < 4; i++)
                async_load16(pb[i] + (size_t)(t + 1) * 8192, Blds[nxt] + wb[i]);
        }
        bf16x8 a[4];
        #pragma unroll
        for (int m = 0; m < 4; m++)
            a[m] = *(const bf16x8*)(Alds[cur] + (kgl*130 + wr*64 + m*16 + lr) * 16);
        #pragma unroll
        for (int n = 0; n < 4; n++) {
            const int cb = wc*64 + n*16 + lr;
            bf16x8 bh = *(const bf16x8*)(Blds[cur] + (kgl*130 + cb) * 16);
            bf16x8 bl = *(const bf16x8*)(Blds[cur] + ((4 + kgl)*130 + cb) * 16);
            #pragma unroll
            for (int m = 0; m < 4; m++) {
                acc[m][n] = __builtin_amdgcn_mfma_f32_16x16x32_bf16(a[m], bl, acc[m][n], 0, 0, 0);
                acc[m][n] = __builtin_amdgcn_mfma_f32_16x16x32_bf16(a[m], bh, acc[m][n], 0, 0, 0);
            }
        }
        __syncthreads();
    }

    #pragma unroll
    for (int n = 0; n < 4; n++) {
        const int gcol = col0 + wc*64 + n*16 + lr;
        const float bv = bo[gcol];
        #pragma unroll
        for (int m = 0; m < 4; m++) {
            #pragma unroll
            for (int reg = 0; reg < 4; reg++) {
                const int grow = row0 + wr*64 + m*16 + kgl*4 + reg;
                io[(size_t)grow * D_ + gcol] = acc[m][n][reg] + bv;
            }
        }
    }
}

// ---------------------------------------------------------------------------
extern "C" void kernel_launch(void* const* d_in, const int* in_sizes, int n_in,
                              void* d_out, int out_size, void* d_ws, size_t ws_size,
                              hipStream_t stream)
{
    const float* query = (const float*)d_in[0];
    const float* key   = (const float*)d_in[1];
    const float* value = (const float*)d_in[2];
    // d_in[3..5]: pattern_matrix, Wp, bp -- mathematically a no-op (mask == 1)
    const float* Wq = (const float*)d_in[6];
    const float* bq = (const float*)d_in[7];
    const float* Wk = (const float*)d_in[8];
    const float* bk = (const float*)d_in[9];
    const float* Wv = (const float*)d_in[10];
    const float* bv = (const float*)d_in[11];
    const float* Wo = (const float*)d_in[12];
    const float* bo = (const float*)d_in[13];

    float*  out = (float*)d_out;
    ushort* ws  = (ushort*)d_ws;
    ushort* qb  = ws;                        // bf16 [g][t][hd], 1/sqrt(32) folded
    ushort* kb  = ws + (size_t)QSZ;          // bf16 [g][t][hd]
    ushort* vb  = ws + (size_t)QSZ * 2;      // bf16 [g][hd][t]
    ushort* ob  = ws + (size_t)QSZ * 3;      // attn out bf16 [row][col]
    ushort* whi = ws + (size_t)QSZ * 4;                    // 4 matrices chunked
    ushort* wlo = ws + (size_t)QSZ * 4 + (size_t)4 * WSZ;  // total ~135 MB

    splitw_kernel<<<dim3(128), 256, 0, stream>>>(Wq, Wk, Wv, Wo, whi, wlo);
    proj_kernel<<<dim3(2, R_ / 128, 3), 256, 0, stream>>>(
        query, key, value, whi, wlo, bq, bk, bv, qb, kb, vb);
    attn_kernel<<<dim3(G_), 384, 0, stream>>>(qb, kb, vb, ob);
    wo_kernel<<<dim3(2, R_ / 128), 256, 0, stream>>>(ob, whi, wlo, bo, out);
}

// Round 7
// 187.882 us; speedup vs baseline: 1.0721x; 1.0721x over previous
//
#include <hip/hip_runtime.h>
#include <math.h>

// Problem constants
#define B_  4
#define N_  170
#define T_  96
#define D_  256
#define H_  8
#define HD_ 32
#define R_  (B_*N_*T_)    // 65280 rows
#define G_  (B_*N_*H_)    // 5440 attention groups
#define GSZ (T_*HD_)      // 3072 elements per group per tensor
#define QSZ (R_*D_)       // 16,711,680 elements per q/k/v buffer (bf16)
#define WSZ (D_*D_)       // 65536 per weight matrix

typedef short  bf16x8 __attribute__((ext_vector_type(8)));
typedef float  f32x4  __attribute__((ext_vector_type(4)));
typedef unsigned int u32;

#define WAITV4   asm volatile("s_waitcnt vmcnt(4)" ::: "memory")
#define WAITV0   asm volatile("s_waitcnt vmcnt(0)" ::: "memory")
#define WAITLGKM asm volatile("s_waitcnt lgkmcnt(0)" ::: "memory")
#define SCHEDB   __builtin_amdgcn_sched_barrier(0)

__device__ __forceinline__ ushort to_bf16(float x)
{
    uint u = __builtin_bit_cast(uint, x);
    u += 0x8000u;                      // round-half-up
    return (ushort)(u >> 16);
}

__device__ __forceinline__ uint pack2(float x0, float x1)
{
    return (uint)to_bf16(x0) | ((uint)to_bf16(x1) << 16);
}

__device__ __forceinline__ uint4 pack8(float4 a0, float4 a1)
{
    uint4 r;
    r.x = pack2(a0.x, a0.y); r.y = pack2(a0.z, a0.w);
    r.z = pack2(a1.x, a1.y); r.w = pack2(a1.z, a1.w);
    return r;
}

// split fp32 pair into packed bf16 hi (truncate; x-hi exact) and lo words
__device__ __forceinline__ void split2(float x0, float x1, uint& hi, uint& lo)
{
    uint u0 = __builtin_bit_cast(uint, x0);
    uint u1 = __builtin_bit_cast(uint, x1);
    hi = (u0 >> 16) | (u1 & 0xFFFF0000u);
    float h0 = __builtin_bit_cast(float, u0 & 0xFFFF0000u);
    float h1 = __builtin_bit_cast(float, u1 & 0xFFFF0000u);
    float l0 = x0 - h0, l1 = x1 - h1;
    uint v0 = __builtin_bit_cast(uint, l0);
    uint v1 = __builtin_bit_cast(uint, l1);
    lo = (v0 >> 16) | (v1 & 0xFFFF0000u);
}

__device__ __forceinline__ void split8(float4 a0, float4 a1, uint4& hi, uint4& lo)
{
    split2(a0.x, a0.y, hi.x, lo.x);
    split2(a0.z, a0.w, hi.y, lo.y);
    split2(a1.x, a1.y, hi.z, lo.z);
    split2(a1.z, a1.w, hi.w, lo.w);
}

// async global->LDS, 16B per lane; lds dest = wave-uniform base + lane*16 (HW)
__device__ __forceinline__ void async_load16(const void* g, void* l)
{
    __builtin_amdgcn_global_load_lds(
        (const u32 __attribute__((address_space(1)))*)g,
        (u32 __attribute__((address_space(3)))*)l,
        16, 0, 0);
}

// ---------------------------------------------------------------------------
// Kernel 0: one-time W prep, chunked layout [k/8][col][8] per matrix.
// mats 0-2 (Wq,Wk,Wv): single ROUNDED bf16 into whi (wlo unused); Wq gets
// 1/sqrt(32) folded in.  mat 3 (Wo): exact truncated hi + lo pair.
// ---------------------------------------------------------------------------
__global__ __launch_bounds__(256)
void splitw_kernel(const float* __restrict__ Wq, const float* __restrict__ Wk,
                   const float* __restrict__ Wv, const float* __restrict__ Wo,
                   ushort* __restrict__ whi, ushort* __restrict__ wlo)
{
    const int gid = blockIdx.x * 256 + threadIdx.x;   // 32768 chunks
    const int mat = gid >> 13;
    const int rem = gid & 8191;
    const int col = rem >> 5;
    const int kc  = rem & 31;
    const float* W = (mat == 0) ? Wq : (mat == 1) ? Wk : (mat == 2) ? Wv : Wo;
    const float s  = (mat == 0) ? 0.17677669529663687f : 1.0f;
    const float* p = W + (size_t)col * D_ + kc * 8;
    float4 a0 = *(const float4*)p;
    float4 a1 = *(const float4*)(p + 4);
    a0.x *= s; a0.y *= s; a0.z *= s; a0.w *= s;
    a1.x *= s; a1.y *= s; a1.z *= s; a1.w *= s;
    const size_t off = (size_t)mat * WSZ + ((size_t)kc * 256 + col) * 8;
    if (mat < 3) {
        *(uint4*)(whi + off) = pack8(a0, a1);    // rounded single bf16
    } else {
        uint4 h, l;
        split8(a0, a1, h, l);
        *(uint4*)(whi + off) = h;
        *(uint4*)(wlo + off) = l;
    }
}

// ---------------------------------------------------------------------------
// Kernel 1: fused Q/K/V projection, counted-vmcnt 2-phase pipeline.
// A (X, HBM): depth-2 register prefetch (sA0/sA1 ping-pong), round->bf16->LDS.
// B (W single rounded bf16, L2-hot): depth-1 global_load_lds double buffer.
// Per-step VMEM order: [A(t+1)(4 in flight) | B(t+1)(2) | A(t+2)(4)]; pack
// auto-waits vmcnt(6); manual vmcnt(4) retires B before the raw s_barrier,
// leaving A(t+2) in flight across it. BM=128, BN=128, BK=32, 4 waves.
// LDS 33 KB -> 4 blocks/CU.
// ---------------------------------------------------------------------------
__global__ __launch_bounds__(256)
void proj_kernel(const float* __restrict__ Xq, const float* __restrict__ Xk,
                 const float* __restrict__ Xv,
                 const ushort* __restrict__ whi,
                 const float* __restrict__ bq, const float* __restrict__ bk,
                 const float* __restrict__ bv,
                 ushort* __restrict__ oq, ushort* __restrict__ ok_,
                 ushort* __restrict__ ov)
{
    const int z = blockIdx.z;
    const float* X    = (z == 0) ? Xq : (z == 1) ? Xk : Xv;
    const float* bias = (z == 0) ? bq : (z == 1) ? bk : bv;
    ushort*      out  = (z == 0) ? oq : (z == 1) ? ok_ : ov;
    const ushort* Wh = whi + (size_t)z * WSZ;

    const int tid  = threadIdx.x;
    const int lane = tid & 63;
    const int w    = tid >> 6;
    const int col0 = blockIdx.x * 128;
    const int row0 = blockIdx.y * 128;
    const int wr   = w >> 1;
    const int wc   = w & 1;
    const int lr   = lane & 15;
    const int kgl  = lane >> 4;

    __shared__ __align__(16) char Alds[2][8320];    // 4 planes x 130 chunks
    __shared__ __align__(16) char Blds[2][8320];    // 4 planes x 130 chunks

    // A stage descriptors: 2 chunks/thread (chunk = 8 bf16 = 16B)
    const int cA1 = tid + 256;
    const int kA0 = tid >> 7, rA0 = tid & 127;
    const int kA1 = cA1 >> 7, rA1 = cA1 & 127;
    const float* pa0 = X + (size_t)(row0 + rA0) * D_ + kA0 * 8;
    const float* pa1 = X + (size_t)(row0 + rA1) * D_ + kA1 * 8;
    const uint wa0 = (uint)(kA0 * 130 + rA0) * 16;
    const uint wa1 = (uint)(kA1 * 130 + rA1) * 16;

    // B stage descriptors: 2 gl_lds issues/wave (64-chunk linear segments)
    const ushort* pb[2];
    uint wb[2];
    #pragma unroll
    for (int i = 0; i < 2; i++) {
        const int s = w * 2 + i, kg = s >> 1, colh = s & 1;
        pb[i] = Wh + ((size_t)kg * 256 + col0 + colh * 64 + lane) * 8;
        wb[i] = (uint)__builtin_amdgcn_readfirstlane((kg * 130 + colh * 64) * 16);
    }

    f32x4 acc[4][4];
    #pragma unroll
    for (int m = 0; m < 4; m++)
        #pragma unroll
        for (int n = 0; n < 4; n++) acc[m][n] = (f32x4)0.f;

    float4 sA0[4], sA1[4];   // two in-flight A register sets (static-indexed)

#define LOADA(t, S)  do { \
        const float* q0_ = pa0 + (t) * 32; \
        const float* q1_ = pa1 + (t) * 32; \
        S[0] = *(const float4*)q0_;  S[1] = *(const float4*)(q0_ + 4); \
        S[2] = *(const float4*)q1_;  S[3] = *(const float4*)(q1_ + 4); \
    } while (0)
#define WRITEA(buf, S) do { \
        *(uint4*)(Alds[buf] + wa0) = pack8(S[0], S[1]); \
        *(uint4*)(Alds[buf] + wa1) = pack8(S[2], S[3]); \
    } while (0)
#define ISSUEB(t, buf) do { \
        _Pragma("unroll") \
        for (int i_ = 0; i_ < 2; i_++) \
            async_load16(pb[i_] + (size_t)(t) * 8192, Blds[buf] + wb[i_]); \
    } while (0)

    // ---- prologue: A[0]->sA0, B[0]->buf0, A[1]->sA1; write A[0]; barrier ----
    LOADA(0, sA0);  SCHEDB;
    ISSUEB(0, 0);   SCHEDB;
    LOADA(1, sA1);  SCHEDB;
    WRITEA(0, sA0);            // compiler auto-waits vmcnt(6) for sA0 here
    WAITLGKM;
    WAITV4;                    // retire B[0]; leave A[1] (4 loads) in flight
    SCHEDB;
    __builtin_amdgcn_s_barrier();
    SCHEDB;

    #pragma unroll
    for (int t = 0; t < 8; t++) {
        const int cur = t & 1, nxt = cur ^ 1;
        if (t < 7) { ISSUEB(t + 1, nxt); SCHEDB; }
        if (t < 6) {
            if (t & 1) LOADA(t + 2, sA1); else LOADA(t + 2, sA0);
            SCHEDB;
        }
        // ---- compute current tile: 16 MFMA ----
        {
            bf16x8 a[4];
            #pragma unroll
            for (int m = 0; m < 4; m++)
                a[m] = *(const bf16x8*)(Alds[cur] + (kgl*130 + wr*64 + m*16 + lr) * 16);
            #pragma unroll
            for (int n = 0; n < 4; n++) {
                const int cb = wc*64 + n*16 + lr;
                bf16x8 bh = *(const bf16x8*)(Blds[cur] + (kgl*130 + cb) * 16);
                #pragma unroll
                for (int m = 0; m < 4; m++)
                    acc[m][n] = __builtin_amdgcn_mfma_f32_16x16x32_bf16(a[m], bh, acc[m][n], 0, 0, 0);
            }
        }
        if (t < 7) {
            // pack A[t+1] (auto vmcnt retires its loads) and stage to nxt
            if (t & 1) WRITEA(nxt, sA0); else WRITEA(nxt, sA1);
            WAITLGKM;
            if (t < 6) { WAITV4; }   // retire B[t+1]; A[t+2] stays in flight
            else       { WAITV0; }   // t==6: retire B[7] (no A[8])
            SCHEDB;
            __builtin_amdgcn_s_barrier();
            SCHEDB;
        }
    }
#undef LOADA
#undef WRITEA
#undef ISSUEB

    // epilogue: + bias -> bf16, head-split store (Wq pre-scaled; bias scaled here)
    const float sc = (z == 0) ? 0.17677669529663687f : 1.0f;
    if (z < 2) {
        #pragma unroll
        for (int n = 0; n < 4; n++) {
            const int gcol = col0 + wc*64 + n*16 + lr;
            const int h    = gcol >> 5;
            const int hd   = gcol & 31;
            const float bvs = bias[gcol] * sc;
            #pragma unroll
            for (int m = 0; m < 4; m++) {
                #pragma unroll
                for (int reg = 0; reg < 4; reg++) {
                    const int grow = row0 + wr*64 + m*16 + kgl*4 + reg;
                    const int bn = grow / T_;
                    const int t  = grow - bn * T_;
                    out[(size_t)((bn*H_ + h)*T_ + t)*HD_ + hd] = to_bf16(acc[m][n][reg] + bvs);
                }
            }
        }
    } else {
        // v: [g][hd][t], pack 4 consecutive t (reg dim) into ushort4
        #pragma unroll
        for (int n = 0; n < 4; n++) {
            const int gcol = col0 + wc*64 + n*16 + lr;
            const int h    = gcol >> 5;
            const int hd   = gcol & 31;
            const float bvs = bias[gcol];
            #pragma unroll
            for (int m = 0; m < 4; m++) {
                const int grow0 = row0 + wr*64 + m*16 + kgl*4;  // 4 | 96 -> one bn
                const int bn = grow0 / T_;
                const int t0 = grow0 - bn * T_;
                ushort4 pk;
                pk.x = to_bf16(acc[m][n][0] + bvs);
                pk.y = to_bf16(acc[m][n][1] + bvs);
                pk.z = to_bf16(acc[m][n][2] + bvs);
                pk.w = to_bf16(acc[m][n][3] + bvs);
                *(ushort4*)&out[(size_t)((bn*H_ + h)*HD_ + hd)*T_ + t0] = pk;
            }
        }
    }
}

// ---------------------------------------------------------------------------
// Kernel 2: MFMA attention, one block per (bn,h), 384 thr = 6 waves.
// O written as SINGLE bf16 row-major [bn*96+t][h*32+hd] for wo_kernel.
// ---------------------------------------------------------------------------
__global__ __launch_bounds__(384)
void attn_kernel(const ushort* __restrict__ q, const ushort* __restrict__ k,
                 const ushort* __restrict__ vt, ushort* __restrict__ Obf)
{
    const int g   = blockIdx.x;
    const int tid = threadIdx.x;
    __shared__ __align__(16) char lds[37888];

    {
        const ushort* Qg = q  + (size_t)g * GSZ;
        const ushort* Kg = k  + (size_t)g * GSZ;
        const ushort* Vg = vt + (size_t)g * GSZ;
        const int t  = tid >> 2, kg = tid & 3;
        uint4 aq = *(const uint4*)(Qg + tid * 8);
        *(uint4*)(lds + kg*1568 + t*16) = aq;
        uint4 ak = *(const uint4*)(Kg + tid * 8);
        *(uint4*)(lds + 6272 + kg*1568 + t*16) = ak;
        const int hd = tid / 12, pl = tid - hd*12;
        uint4 av = *(const uint4*)(Vg + tid * 8);
        *(uint4*)(lds + 12544 + pl*544 + hd*16) = av;
    }
    __syncthreads();

    const int w = tid >> 6, lane = tid & 63;
    const int lr = lane & 15, kgl = lane >> 4;

    f32x4 acc[6];
    {
        bf16x8 aq = *(const bf16x8*)(lds + kgl*1568 + (w*16 + lr)*16);
        #pragma unroll
        for (int n = 0; n < 6; n++) {
            bf16x8 bk = *(const bf16x8*)(lds + 6272 + kgl*1568 + (n*16 + lr)*16);
            acc[n] = __builtin_amdgcn_mfma_f32_16x16x32_bf16(aq, bk, (f32x4)0.f, 0, 0, 0);
        }
    }

    float mx[4], sm[4], inv[4];
    #pragma unroll
    for (int reg = 0; reg < 4; reg++) {
        float m = acc[0][reg];
        #pragma unroll
        for (int n = 1; n < 6; n++) m = fmaxf(m, acc[n][reg]);
        mx[reg] = m;
    }
    #pragma unroll
    for (int off = 1; off < 16; off <<= 1)
        #pragma unroll
        for (int reg = 0; reg < 4; reg++)
            mx[reg] = fmaxf(mx[reg], __shfl_xor(mx[reg], off));
    #pragma unroll
    for (int reg = 0; reg < 4; reg++) sm[reg] = 0.f;
    #pragma unroll
    for (int n = 0; n < 6; n++)
        #pragma unroll
        for (int reg = 0; reg < 4; reg++) {
            float e = __expf(acc[n][reg] - mx[reg]);
            acc[n][reg] = e;
            sm[reg] += e;
        }
    #pragma unroll
    for (int off = 1; off < 16; off <<= 1)
        #pragma unroll
        for (int reg = 0; reg < 4; reg++)
            sm[reg] += __shfl_xor(sm[reg], off);
    #pragma unroll
    for (int reg = 0; reg < 4; reg++) inv[reg] = 1.0f / sm[reg];

    #pragma unroll
    for (int n = 0; n < 6; n++) {
        const int pl = (n >> 1)*4 + ((n*2 + (lr >> 3)) & 3);
        const int j  = lr & 7;
        #pragma unroll
        for (int reg = 0; reg < 4; reg++) {
            const int row = w*16 + kgl*4 + reg;
            *(ushort*)(lds + 19072 + pl*1568 + row*16 + j*2) =
                to_bf16(acc[n][reg] * inv[reg]);
        }
    }
    __syncthreads();

    f32x4 o[2] = {(f32x4)0.f, (f32x4)0.f};
    #pragma unroll
    for (int ks = 0; ks < 3; ks++) {
        bf16x8 ap = *(const bf16x8*)(lds + 19072 + (ks*4 + kgl)*1568 + (w*16 + lr)*16);
        #pragma unroll
        for (int n2 = 0; n2 < 2; n2++) {
            bf16x8 bv = *(const bf16x8*)(lds + 12544 + (ks*4 + kgl)*544 + (n2*16 + lr)*16);
            o[n2] = __builtin_amdgcn_mfma_f32_16x16x32_bf16(ap, bv, o[n2], 0, 0, 0);
        }
    }

    const int bn = g >> 3, h = g & 7;
    const size_t rb = (size_t)(bn * T_) * D_ + h * HD_;
    #pragma unroll
    for (int n2 = 0; n2 < 2; n2++)
        #pragma unroll
        for (int reg = 0; reg < 4; reg++) {
            const int qr = w*16 + kgl*4 + reg;
            Obf[rb + (size_t)qr * D_ + n2*16 + lr] = to_bf16(o[n2][reg]);
        }
}

// ---------------------------------------------------------------------------
// Kernel 3: d_out = O @ Wo^T + bo. A (O bf16) and B (Wo hi/lo) both via
// global_load_lds, 2-phase double-buffered loop.
// BM=128, BN=128, BK=32, 256 thr = 4 waves.
// ---------------------------------------------------------------------------
__global__ __launch_bounds__(256)
void wo_kernel(const ushort* __restrict__ Obf,
               const ushort* __restrict__ whi, const ushort* __restrict__ wlo,
               const float* __restrict__ bo, float* __restrict__ io)
{
    const int tid  = threadIdx.x;
    const int lane = tid & 63;
    const int w    = tid >> 6;
    const int col0 = blockIdx.x * 128;
    const int row0 = blockIdx.y * 128;
    const int wr   = w >> 1;
    const int wc   = w & 1;
    const int lr   = lane & 15;
    const int kgl  = lane >> 4;
    const ushort* Wh = whi + (size_t)3 * WSZ;
    const ushort* Wl = wlo + (size_t)3 * WSZ;

    __shared__ __align__(16) char Alds[2][8320];
    __shared__ __align__(16) char Blds[2][16640];

    // A: 2 gl_lds issues/wave (s = w*2+i: kg = s>>1, rhalf = s&1)
    const ushort* pa[2];
    uint wa[2];
    #pragma unroll
    for (int i = 0; i < 2; i++) {
        const int s = w * 2 + i, kg = s >> 1, rhalf = s & 1;
        pa[i] = Obf + (size_t)(row0 + rhalf * 64 + lane) * D_ + kg * 8;
        wa[i] = (uint)__builtin_amdgcn_readfirstlane((kg * 130 + rhalf * 64) * 16);
    }
    // B: 4 gl_lds issues/wave
    const ushort* pb[4];
    uint wb[4];
    #pragma unroll
    for (int i = 0; i < 4; i++) {
        const int s = w * 4 + i, hl = s >> 3, kg = (s >> 1) & 3, colh = s & 1;
        pb[i] = (hl ? Wl : Wh) + ((size_t)kg * 256 + col0 + colh * 64 + lane) * 8;
        wb[i] = (uint)__builtin_amdgcn_readfirstlane(
                    (((hl * 4 + kg) * 130) + colh * 64) * 16);
    }

    f32x4 acc[4][4];
    #pragma unroll
    for (int m = 0; m < 4; m++)
        #pragma unroll
        for (int n = 0; n < 4; n++) acc[m][n] = (f32x4)0.f;

    // prologue
    #pragma unroll
    for (int i = 0; i < 2; i++) async_load16(pa[i], Alds[0] + wa[i]);
    #pragma unroll
    for (int i = 0; i < 4; i++) async_load16(pb[i], Blds[0] + wb[i]);
    __syncthreads();

    for (int t = 0; t < 8; t++) {
        const int cur = t & 1, nxt = cur ^ 1;
        if (t < 7) {
            #pragma unroll
            for (int i = 0; i < 2; i++)
                async_load16(pa[i] + (size_t)(t + 1) * 32, Alds[nxt] + wa[i]);
            #pragma unroll
            for (int i = 0; i < 4; i++)
                async_load16(pb[i] + (size_t)(t + 1) * 8192, Blds[nxt] + wb[i]);
        }
        bf16x8 a[4];
        #pragma unroll
        for (int m = 0; m < 4; m++)
            a[m] = *(const bf16x8*)(Alds[cur] + (kgl*130 + wr*64 + m*16 + lr) * 16);
        #pragma unroll
        for (int n = 0; n < 4; n++) {
            const int cb = wc*64 + n*16 + lr;
            bf16x8 bh = *(const bf16x8*)(Blds[cur] + (kgl*130 + cb) * 16);
            bf16x8 bl = *(const bf16x8*)(Blds[cur] + ((4 + kgl)*130 + cb) * 16);
            #pragma unroll
            for (int m = 0; m < 4; m++) {
                acc[m][n] = __builtin_amdgcn_mfma_f32_16x16x32_bf16(a[m], bl, acc[m][n], 0, 0, 0);
                acc[m][n] = __builtin_amdgcn_mfma_f32_16x16x32_bf16(a[m], bh, acc[m][n], 0, 0, 0);
            }
        }
        __syncthreads();
    }

    #pragma unroll
    for (int n = 0; n < 4; n++) {
        const int gcol = col0 + wc*64 + n*16 + lr;
        const float bv = bo[gcol];
        #pragma unroll
        for (int m = 0; m < 4; m++) {
            #pragma unroll
            for (int reg = 0; reg < 4; reg++) {
                const int grow = row0 + wr*64 + m*16 + kgl*4 + reg;
                io[(size_t)grow * D_ + gcol] = acc[m][n][reg] + bv;
            }
        }
    }
}

// ---------------------------------------------------------------------------
extern "C" void kernel_launch(void* const* d_in, const int* in_sizes, int n_in,
                              void* d_out, int out_size, void* d_ws, size_t ws_size,
                              hipStream_t stream)
{
    const float* query = (const float*)d_in[0];
    const float* key   = (const float*)d_in[1];
    const float* value = (const float*)d_in[2];
    // d_in[3..5]: pattern_matrix, Wp, bp -- mathematically a no-op (mask == 1)
    const float* Wq = (const float*)d_in[6];
    const float* bq = (const float*)d_in[7];
    const float* Wk = (const float*)d_in[8];
    const float* bk = (const float*)d_in[9];
    const float* Wv = (const float*)d_in[10];
    const float* bv = (const float*)d_in[11];
    const float* Wo = (const float*)d_in[12];
    const float* bo = (const float*)d_in[13];

    float*  out = (float*)d_out;
    ushort* ws  = (ushort*)d_ws;
    ushort* qb  = ws;                        // bf16 [g][t][hd], 1/sqrt(32) folded
    ushort* kb  = ws + (size_t)QSZ;          // bf16 [g][t][hd]
    ushort* vb  = ws + (size_t)QSZ * 2;      // bf16 [g][hd][t]
    ushort* ob  = ws + (size_t)QSZ * 3;      // attn out bf16 [row][col]
    ushort* whi = ws + (size_t)QSZ * 4;                    // 4 matrices chunked
    ushort* wlo = ws + (size_t)QSZ * 4 + (size_t)4 * WSZ;  // total ~135 MB

    splitw_kernel<<<dim3(128), 256, 0, stream>>>(Wq, Wk, Wv, Wo, whi, wlo);
    proj_kernel<<<dim3(2, R_ / 128, 3), 256, 0, stream>>>(
        query, key, value, whi, bq, bk, bv, qb, kb, vb);
    attn_kernel<<<dim3(G_), 384, 0, stream>>>(qb, kb, vb, ob);
    wo_kernel<<<dim3(2, R_ / 128), 256, 0, stream>>>(ob, whi, wlo, bo, out);
}

// Round 8
// 133.000 us; speedup vs baseline: 1.5145x; 1.4126x over previous
//
#include <hip/hip_runtime.h>
#include <math.h>

// Problem constants
#define B_  4
#define N_  170
#define T_  96
#define D_  256
#define H_  8
#define HD_ 32
#define R_  (B_*N_*T_)    // 65280 rows
#define BN_ (B_*N_)       // 680 (bn) blocks
#define WSZ (D_*D_)       // 65536 per weight matrix

typedef short  bf16x8 __attribute__((ext_vector_type(8)));
typedef float  f32x4  __attribute__((ext_vector_type(4)));

// ---- LDS map (bytes) -------------------------------------------------------
// X region: 32 planes x 1568 (X planes -> per-wave P scratch -> O planes)
#define XB   0
// K planes: [h][kg 0..3][t 0..95][8bf16], plane stride 1568
#define KB   50176
// V region: q planes ([h][kg][t][8], stride 1568) then v planes
//           ([h][kvkg 0..11][hd 0..31][8], plane stride 544)
#define VB   100352
#define LDSZ 152576       // <= 160 KiB

__device__ __forceinline__ ushort to_bf16(float x)
{
    uint u = __builtin_bit_cast(uint, x);
    u += 0x8000u;                      // round-half-up
    return (ushort)(u >> 16);
}

__device__ __forceinline__ uint pack2(float x0, float x1)
{
    return (uint)to_bf16(x0) | ((uint)to_bf16(x1) << 16);
}

__device__ __forceinline__ uint4 pack8(float4 a0, float4 a1)
{
    uint4 r;
    r.x = pack2(a0.x, a0.y); r.y = pack2(a0.z, a0.w);
    r.z = pack2(a1.x, a1.y); r.w = pack2(a1.z, a1.w);
    return r;
}

#define MFMA(a, b, c) __builtin_amdgcn_mfma_f32_16x16x32_bf16((a), (b), (c), 0, 0, 0)

// ---------------------------------------------------------------------------
// Kernel 0: W prep. W[col][k] fp32 -> single ROUNDED bf16, chunked layout
// [k/8][col][8] per matrix. Wq gets 1/sqrt(32) folded in. 0=Wq 1=Wk 2=Wv 3=Wo.
// ---------------------------------------------------------------------------
__global__ __launch_bounds__(256)
void splitw_kernel(const float* __restrict__ Wq, const float* __restrict__ Wk,
                   const float* __restrict__ Wv, const float* __restrict__ Wo,
                   ushort* __restrict__ whi)
{
    const int gid = blockIdx.x * 256 + threadIdx.x;   // 32768 chunks
    const int mat = gid >> 13;
    const int rem = gid & 8191;
    const int col = rem >> 5;
    const int kc  = rem & 31;
    const float* W = (mat == 0) ? Wq : (mat == 1) ? Wk : (mat == 2) ? Wv : Wo;
    const float s  = (mat == 0) ? 0.17677669529663687f : 1.0f;
    const float* p = W + (size_t)col * D_ + kc * 8;
    float4 a0 = *(const float4*)p;
    float4 a1 = *(const float4*)(p + 4);
    a0.x *= s; a0.y *= s; a0.z *= s; a0.w *= s;
    a1.x *= s; a1.y *= s; a1.z *= s; a1.w *= s;
    const size_t off = (size_t)mat * WSZ + ((size_t)kc * 256 + col) * 8;
    *(uint4*)(whi + off) = pack8(a0, a1);
}

// ---------------------------------------------------------------------------
// Mega kernel: one block per bn. 768 threads = 12 waves.
// Attention partition: wave wv -> (irow = wv>>1: q-rows 16*irow.., jhalf = wv&1:
// heads 4*jhalf..). GEMM d-tile partition (exclusive, no W redundancy):
// wave wv owns d-tiles {wv} u {12+wv if wv<4}.
// Phases: stageXq | q^T GEMM -> q planes | q->regs, Xk->LDS | k^T GEMM -> K |
// Xv->LDS | v GEMM -> V | attention (per-wave scratch) | O->LDS | wo GEMM -> out
// ---------------------------------------------------------------------------
__global__ __launch_bounds__(768, 3)
void mega_kernel(const float* __restrict__ Xq, const float* __restrict__ Xk,
                 const float* __restrict__ Xv, const ushort* __restrict__ W,
                 const float* __restrict__ bq, const float* __restrict__ bk,
                 const float* __restrict__ bv, const float* __restrict__ bo,
                 float* __restrict__ out)
{
    __shared__ __align__(16) char lds[LDSZ];

    const int bn   = blockIdx.x;
    const int tid  = threadIdx.x;
    const int wv   = tid >> 6;
    const int lane = tid & 63;
    const int lr   = lane & 15;
    const int kgl  = lane >> 4;
    const int irow = wv >> 1;        // q-row tile for attention
    const int jhalf = wv & 1;        // head-half for attention
    const bool hasB = (wv < 4);
    const int mtA = wv, mtB = 12 + wv;
    const size_t xoff = (size_t)bn * T_ * D_;

    // ---- stage Xq -> X planes (bf16) ----
    #pragma unroll
    for (int c = 0; c < 4; c++) {
        const int cc = tid + c * 768;
        const int row = cc % 96, kc = cc / 96;
        const float* p = Xq + xoff + row * D_ + kc * 8;
        float4 a0 = *(const float4*)p, a1 = *(const float4*)(p + 4);
        *(uint4*)(lds + XB + kc * 1568 + row * 16) = pack8(a0, a1);
    }
    __syncthreads();                               // (1)

    // ---- prefetch Xk into regs (flies under q-GEMM) ----
    float4 pf[8];
    #pragma unroll
    for (int c = 0; c < 4; c++) {
        const int cc = tid + c * 768;
        const int row = cc % 96, kc = cc / 96;
        const float* p = Xk + xoff + row * D_ + kc * 8;
        pf[2*c] = *(const float4*)p; pf[2*c+1] = *(const float4*)(p + 4);
    }

    // ---- q^T GEMM: M = d (Wq), N = t (Xq). acc lane -> (col t = lr, row d) ----
    f32x4 accq[2][6];
    #pragma unroll
    for (int u = 0; u < 2; u++)
        #pragma unroll
        for (int nt = 0; nt < 6; nt++) accq[u][nt] = (f32x4)0.f;
    {
        const ushort* Wq = W;   // pre-scaled by 1/sqrt(32)
        #pragma unroll
        for (int ks = 0; ks < 8; ks++) {
            bf16x8 wa0 = *(const bf16x8*)(Wq + ((size_t)(ks*4+kgl)*256 + mtA*16 + lr)*8);
            bf16x8 wa1{};
            if (hasB) wa1 = *(const bf16x8*)(Wq + ((size_t)(ks*4+kgl)*256 + mtB*16 + lr)*8);
            #pragma unroll
            for (int nt = 0; nt < 6; nt++) {
                bf16x8 xb = *(const bf16x8*)(lds + XB + (ks*4+kgl)*1568 + (nt*16+lr)*16);
                accq[0][nt] = MFMA(wa0, xb, accq[0][nt]);
                if (hasB) accq[1][nt] = MFMA(wa1, xb, accq[1][nt]);
            }
        }
    }
    // q epilogue: + s*bq -> bf16 q-planes in V region ([h][kg][t][8])
    {
        const float qs = 0.17677669529663687f;
        #pragma unroll
        for (int u = 0; u < 2; u++) {
            if (u && !hasB) break;
            const int mt = u ? mtB : mtA;
            float4 b4 = *(const float4*)(bq + mt*16 + kgl*4);
            const int h  = mt >> 1;
            const int kg = (mt & 1)*2 + (kgl >> 1);
            char* base = lds + VB + h*6272 + kg*1568 + (kgl & 1)*8;
            #pragma unroll
            for (int nt = 0; nt < 6; nt++) {
                ushort4 o;
                o.x = to_bf16(accq[u][nt][0] + b4.x*qs);
                o.y = to_bf16(accq[u][nt][1] + b4.y*qs);
                o.z = to_bf16(accq[u][nt][2] + b4.z*qs);
                o.w = to_bf16(accq[u][nt][3] + b4.w*qs);
                *(ushort4*)(base + (nt*16+lr)*16) = o;
            }
        }
    }
    __syncthreads();                               // (2)

    // ---- write Xk planes; pull q B-frags into regs; prefetch Xv ----
    #pragma unroll
    for (int c = 0; c < 4; c++) {
        const int cc = tid + c * 768;
        const int row = cc % 96, kc = cc / 96;
        *(uint4*)(lds + XB + kc * 1568 + row * 16) = pack8(pf[2*c], pf[2*c+1]);
    }
    bf16x8 qf[4];
    #pragma unroll
    for (int hh = 0; hh < 4; hh++) {
        const int h = jhalf*4 + hh;
        qf[hh] = *(const bf16x8*)(lds + VB + h*6272 + kgl*1568 + (irow*16+lr)*16);
    }
    #pragma unroll
    for (int c = 0; c < 4; c++) {
        const int cc = tid + c * 768;
        const int row = cc % 96, kc = cc / 96;
        const float* p = Xv + xoff + row * D_ + kc * 8;
        pf[2*c] = *(const float4*)p; pf[2*c+1] = *(const float4*)(p + 4);
    }
    __syncthreads();                               // (3)

    // ---- k^T GEMM -> K planes ----
    {
        f32x4 acck[2][6];
        #pragma unroll
        for (int u = 0; u < 2; u++)
            #pragma unroll
            for (int nt = 0; nt < 6; nt++) acck[u][nt] = (f32x4)0.f;
        const ushort* Wk = W + WSZ;
        #pragma unroll
        for (int ks = 0; ks < 8; ks++) {
            bf16x8 wa0 = *(const bf16x8*)(Wk + ((size_t)(ks*4+kgl)*256 + mtA*16 + lr)*8);
            bf16x8 wa1{};
            if (hasB) wa1 = *(const bf16x8*)(Wk + ((size_t)(ks*4+kgl)*256 + mtB*16 + lr)*8);
            #pragma unroll
            for (int nt = 0; nt < 6; nt++) {
                bf16x8 xb = *(const bf16x8*)(lds + XB + (ks*4+kgl)*1568 + (nt*16+lr)*16);
                acck[0][nt] = MFMA(wa0, xb, acck[0][nt]);
                if (hasB) acck[1][nt] = MFMA(wa1, xb, acck[1][nt]);
            }
        }
        #pragma unroll
        for (int u = 0; u < 2; u++) {
            if (u && !hasB) break;
            const int mt = u ? mtB : mtA;
            float4 b4 = *(const float4*)(bk + mt*16 + kgl*4);
            const int h  = mt >> 1;
            const int kg = (mt & 1)*2 + (kgl >> 1);
            char* base = lds + KB + h*6272 + kg*1568 + (kgl & 1)*8;
            #pragma unroll
            for (int nt = 0; nt < 6; nt++) {
                ushort4 o;
                o.x = to_bf16(acck[u][nt][0] + b4.x);
                o.y = to_bf16(acck[u][nt][1] + b4.y);
                o.z = to_bf16(acck[u][nt][2] + b4.z);
                o.w = to_bf16(acck[u][nt][3] + b4.w);
                *(ushort4*)(base + (nt*16+lr)*16) = o;
            }
        }
    }
    __syncthreads();                               // (4)

    // ---- write Xv planes ----
    #pragma unroll
    for (int c = 0; c < 4; c++) {
        const int cc = tid + c * 768;
        const int row = cc % 96, kc = cc / 96;
        *(uint4*)(lds + XB + kc * 1568 + row * 16) = pack8(pf[2*c], pf[2*c+1]);
    }
    __syncthreads();                               // (5)

    // ---- v GEMM (normal): M = t (Xv), N = d (Wv). -> V planes [h][kvkg][hd][8]
    {
        f32x4 accv[6][2];
        #pragma unroll
        for (int mt = 0; mt < 6; mt++) { accv[mt][0] = (f32x4)0.f; accv[mt][1] = (f32x4)0.f; }
        const ushort* Wv = W + 2*WSZ;
        #pragma unroll
        for (int ks = 0; ks < 8; ks++) {
            bf16x8 wb0 = *(const bf16x8*)(Wv + ((size_t)(ks*4+kgl)*256 + mtA*16 + lr)*8);
            bf16x8 wb1{};
            if (hasB) wb1 = *(const bf16x8*)(Wv + ((size_t)(ks*4+kgl)*256 + mtB*16 + lr)*8);
            #pragma unroll
            for (int mt = 0; mt < 6; mt++) {
                bf16x8 xa = *(const bf16x8*)(lds + XB + (ks*4+kgl)*1568 + (mt*16+lr)*16);
                accv[mt][0] = MFMA(xa, wb0, accv[mt][0]);
                if (hasB) accv[mt][1] = MFMA(xa, wb1, accv[mt][1]);
            }
        }
        #pragma unroll
        for (int u = 0; u < 2; u++) {
            if (u && !hasB) break;
            const int nt = u ? mtB : mtA;
            const float bvv = bv[nt*16 + lr];
            const int h  = nt >> 1;
            const int hd = (nt & 1)*16 + lr;
            char* base = lds + VB + h*6528 + hd*16 + (kgl & 1)*8;
            #pragma unroll
            for (int mt = 0; mt < 6; mt++) {
                const int kvkg = mt*2 + (kgl >> 1);
                ushort4 o;
                o.x = to_bf16(accv[mt][u][0] + bvv);
                o.y = to_bf16(accv[mt][u][1] + bvv);
                o.z = to_bf16(accv[mt][u][2] + bvv);
                o.w = to_bf16(accv[mt][u][3] + bvv);
                *(ushort4*)(base + kvkg*544) = o;
            }
        }
    }
    __syncthreads();                               // (6)

    // ---- attention: 4 heads per wave; swapped QK^T, in-reg softmax,
    //      P via per-wave 3KB scratch (in freed X region), PV ----
    f32x4 oacc[4][2];
    #pragma unroll
    for (int hh = 0; hh < 4; hh++) { oacc[hh][0] = (f32x4)0.f; oacc[hh][1] = (f32x4)0.f; }
    {
        char* sw = lds + XB + wv * 3264;           // 12 planes x 272B
        #pragma unroll
        for (int hh = 0; hh < 4; hh++) {
            const int h = jhalf*4 + hh;
            f32x4 s[6];
            #pragma unroll
            for (int mt = 0; mt < 6; mt++) {
                bf16x8 kf = *(const bf16x8*)(lds + KB + h*6272 + kgl*1568 + (mt*16+lr)*16);
                s[mt] = MFMA(kf, qf[hh], (f32x4)0.f);    // M=kv rows, N=q col=lr
            }
            float mx = s[0][0];
            #pragma unroll
            for (int mt = 0; mt < 6; mt++)
                #pragma unroll
                for (int r = 0; r < 4; r++) mx = fmaxf(mx, s[mt][r]);
            mx = fmaxf(mx, __shfl_xor(mx, 16));
            mx = fmaxf(mx, __shfl_xor(mx, 32));
            float sum = 0.f;
            #pragma unroll
            for (int mt = 0; mt < 6; mt++)
                #pragma unroll
                for (int r = 0; r < 4; r++) {
                    float e = __expf(s[mt][r] - mx);
                    s[mt][r] = e; sum += e;
                }
            sum += __shfl_xor(sum, 16);
            sum += __shfl_xor(sum, 32);
            const float inv = 1.f / sum;
            #pragma unroll
            for (int mt = 0; mt < 6; mt++) {
                uint u0 = pack2(s[mt][0]*inv, s[mt][1]*inv);
                uint u1 = pack2(s[mt][2]*inv, s[mt][3]*inv);
                char* pb = sw + (mt*2 + (kgl>>1))*272 + lr*16 + (kgl&1)*8;
                *(uint*)pb = u0; *(uint*)(pb + 4) = u1;
            }
            #pragma unroll
            for (int s2 = 0; s2 < 3; s2++) {
                bf16x8 pa = *(const bf16x8*)(sw + (s2*4+kgl)*272 + lr*16);
                #pragma unroll
                for (int n2 = 0; n2 < 2; n2++) {
                    bf16x8 vf = *(const bf16x8*)(lds + VB + h*6528 + (s2*4+kgl)*544 + (n2*16+lr)*16);
                    oacc[hh][n2] = MFMA(pa, vf, oacc[hh][n2]);
                }
            }
        }
    }
    __syncthreads();                               // (7) scratch dead

    // ---- O -> O planes (X region), bf16 ----
    #pragma unroll
    for (int hh = 0; hh < 4; hh++)
        #pragma unroll
        for (int n2 = 0; n2 < 2; n2++) {
            const int dcol = jhalf*128 + hh*32 + n2*16 + lr;
            char* base = lds + XB + (dcol >> 3)*1568 + (dcol & 7)*2;
            #pragma unroll
            for (int r = 0; r < 4; r++) {
                const int t = irow*16 + kgl*4 + r;
                *(ushort*)(base + t*16) = to_bf16(oacc[hh][n2][r]);
            }
        }
    __syncthreads();                               // (8)

    // ---- wo GEMM: M = t (O planes), N = d (Wo). -> d_out fp32 + bo ----
    {
        f32x4 acco[6][2];
        #pragma unroll
        for (int mt = 0; mt < 6; mt++) { acco[mt][0] = (f32x4)0.f; acco[mt][1] = (f32x4)0.f; }
        const ushort* Wo = W + 3*WSZ;
        #pragma unroll
        for (int ks = 0; ks < 8; ks++) {
            bf16x8 wb0 = *(const bf16x8*)(Wo + ((size_t)(ks*4+kgl)*256 + mtA*16 + lr)*8);
            bf16x8 wb1{};
            if (hasB) wb1 = *(const bf16x8*)(Wo + ((size_t)(ks*4+kgl)*256 + mtB*16 + lr)*8);
            #pragma unroll
            for (int mt = 0; mt < 6; mt++) {
                bf16x8 oa = *(const bf16x8*)(lds + XB + (ks*4+kgl)*1568 + (mt*16+lr)*16);
                acco[mt][0] = MFMA(oa, wb0, acco[mt][0]);
                if (hasB) acco[mt][1] = MFMA(oa, wb1, acco[mt][1]);
            }
        }
        #pragma unroll
        for (int u = 0; u < 2; u++) {
            if (u && !hasB) break;
            const int nt = u ? mtB : mtA;
            const float bod = bo[nt*16 + lr];
            #pragma unroll
            for (int mt = 0; mt < 6; mt++)
                #pragma unroll
                for (int r = 0; r < 4; r++) {
                    const int t = mt*16 + kgl*4 + r;
                    out[((size_t)(bn*T_ + t))*D_ + nt*16 + lr] = acco[mt][u][r] + bod;
                }
        }
    }
}

// ---------------------------------------------------------------------------
extern "C" void kernel_launch(void* const* d_in, const int* in_sizes, int n_in,
                              void* d_out, int out_size, void* d_ws, size_t ws_size,
                              hipStream_t stream)
{
    const float* query = (const float*)d_in[0];
    const float* key   = (const float*)d_in[1];
    const float* value = (const float*)d_in[2];
    // d_in[3..5]: pattern_matrix, Wp, bp -- mathematically a no-op (mask == 1)
    const float* Wq = (const float*)d_in[6];
    const float* bq = (const float*)d_in[7];
    const float* Wk = (const float*)d_in[8];
    const float* bk = (const float*)d_in[9];
    const float* Wv = (const float*)d_in[10];
    const float* bv = (const float*)d_in[11];
    const float* Wo = (const float*)d_in[12];
    const float* bo = (const float*)d_in[13];

    float*  out = (float*)d_out;
    ushort* whi = (ushort*)d_ws;   // 4 matrices, chunked bf16: 512 KB

    splitw_kernel<<<dim3(128), 256, 0, stream>>>(Wq, Wk, Wv, Wo, whi);
    mega_kernel<<<dim3(BN_), 768, 0, stream>>>(
        query, key, value, whi, bq, bk, bv, bo, out);
}

// Round 9
// 101.631 us; speedup vs baseline: 1.9819x; 1.3087x over previous
//
#include <hip/hip_runtime.h>
#include <math.h>

// Problem constants
#define B_  4
#define N_  170
#define T_  96
#define D_  256
#define H_  8
#define HD_ 32
#define BN_ (B_*N_)       // 680 (bn) blocks
#define WSZ (D_*D_)       // 65536 per weight matrix

typedef short  bf16x8 __attribute__((ext_vector_type(8)));
typedef float  f32x4  __attribute__((ext_vector_type(4)));

// ---- LDS map (bytes). All tiles use 256B sub-planes: [..][kgl][lr][16B] ----
// X region: [ks 0..7][rt 0..5][kgl 0..3] planes -> also P scratch & O planes
#define XB   0
// K: [h][rt 0..5][kg 0..3] planes       (element (h, kg, t, j))
#define KB   49152
// q planes (same layout as K) then V: [h][s2 0..2][n2 0..1][kg 0..3] planes
#define VB   98304
#define LDSZ 147456

__device__ __forceinline__ ushort to_bf16(float x)
{
    uint u = __builtin_bit_cast(uint, x);
    u += 0x8000u;                      // round-half-up
    return (ushort)(u >> 16);
}

__device__ __forceinline__ uint pack2(float x0, float x1)
{
    return (uint)to_bf16(x0) | ((uint)to_bf16(x1) << 16);
}

__device__ __forceinline__ uint4 pack8(float4 a0, float4 a1)
{
    uint4 r;
    r.x = pack2(a0.x, a0.y); r.y = pack2(a0.z, a0.w);
    r.z = pack2(a1.x, a1.y); r.w = pack2(a1.z, a1.w);
    return r;
}

#define MFMA(a, b, c) __builtin_amdgcn_mfma_f32_16x16x32_bf16((a), (b), (c), 0, 0, 0)

// ---------------------------------------------------------------------------
// Kernel 0: W prep. W[col][k] fp32 -> single ROUNDED bf16, chunked layout
// [k/8][col][8] per matrix. Wq gets 1/sqrt(32) folded in. 0=Wq 1=Wk 2=Wv 3=Wo.
// ---------------------------------------------------------------------------
__global__ __launch_bounds__(256)
void splitw_kernel(const float* __restrict__ Wq, const float* __restrict__ Wk,
                   const float* __restrict__ Wv, const float* __restrict__ Wo,
                   ushort* __restrict__ whi)
{
    const int gid = blockIdx.x * 256 + threadIdx.x;   // 32768 chunks
    const int mat = gid >> 13;
    const int rem = gid & 8191;
    const int col = rem >> 5;
    const int kc  = rem & 31;
    const float* W = (mat == 0) ? Wq : (mat == 1) ? Wk : (mat == 2) ? Wv : Wo;
    const float s  = (mat == 0) ? 0.17677669529663687f : 1.0f;
    const float* p = W + (size_t)col * D_ + kc * 8;
    float4 a0 = *(const float4*)p;
    float4 a1 = *(const float4*)(p + 4);
    a0.x *= s; a0.y *= s; a0.z *= s; a0.w *= s;
    a1.x *= s; a1.y *= s; a1.z *= s; a1.w *= s;
    const size_t off = (size_t)mat * WSZ + ((size_t)kc * 256 + col) * 8;
    *(uint4*)(whi + off) = pack8(a0, a1);
}

// ---------------------------------------------------------------------------
// Mega kernel: one block per bn. 1024 threads = 16 waves, 4/SIMD.
// Each wave owns EXACTLY one d-tile (wv) in all 4 GEMMs (balanced), and
// (head h = wv>>1, irow half = wv&1 -> 3 row tiles) in attention (balanced).
// W fragments preloaded per GEMM phase (breaks the L2-latency chain).
// ---------------------------------------------------------------------------
__global__ __launch_bounds__(1024)
void mega_kernel(const float* __restrict__ Xq, const float* __restrict__ Xk,
                 const float* __restrict__ Xv, const ushort* __restrict__ W,
                 const float* __restrict__ bq, const float* __restrict__ bk,
                 const float* __restrict__ bv, const float* __restrict__ bo,
                 float* __restrict__ out)
{
    __shared__ __align__(16) char lds[LDSZ];

    const int bn   = blockIdx.x;
    const int tid  = threadIdx.x;
    const int wv   = tid >> 6;       // 0..15
    const int lane = tid & 63;
    const int lr   = lane & 15;
    const int kgl  = lane >> 4;
    const int h    = wv >> 1;        // attention head for this wave
    const int ib   = (wv & 1) * 3;   // irow base (rows ib*16 .. )
    const size_t xoff = (size_t)bn * T_ * D_;

    // staging chunk coords: 3 chunks/thread (chunk = 8 elems)
    int srow[3], skc[3]; uint saddr[3];
    #pragma unroll
    for (int c = 0; c < 3; c++) {
        const int cc = tid + c * 1024;
        const int row = cc % 96, kc = cc / 96;
        srow[c] = row; skc[c] = kc;
        saddr[c] = (uint)(((((kc >> 2) * 6 + (row >> 4)) * 4 + (kc & 3)) * 256)
                          + (row & 15) * 16);
    }

    // ---- stage Xq -> X planes (bf16) ----
    #pragma unroll
    for (int c = 0; c < 3; c++) {
        const float* p = Xq + xoff + srow[c] * D_ + skc[c] * 8;
        float4 a0 = *(const float4*)p, a1 = *(const float4*)(p + 4);
        *(uint4*)(lds + XB + saddr[c]) = pack8(a0, a1);
    }
    __syncthreads();                               // (1)

    // ---- prefetch Xk into regs (flies under q-GEMM) ----
    float4 pf[6];
    #pragma unroll
    for (int c = 0; c < 3; c++) {
        const float* p = Xk + xoff + srow[c] * D_ + skc[c] * 8;
        pf[2*c] = *(const float4*)p; pf[2*c+1] = *(const float4*)(p + 4);
    }

    // ---- q^T GEMM: M = d (tile wv), N = t. acc: col t = lr, row d = kgl*4+r
    {
        bf16x8 wf[8];
        #pragma unroll
        for (int ks = 0; ks < 8; ks++)
            wf[ks] = *(const bf16x8*)(W + ((size_t)(ks*4+kgl)*256 + wv*16 + lr)*8);
        f32x4 acc[6];
        #pragma unroll
        for (int nt = 0; nt < 6; nt++) acc[nt] = (f32x4)0.f;
        #pragma unroll
        for (int ks = 0; ks < 8; ks++)
            #pragma unroll
            for (int nt = 0; nt < 6; nt++) {
                bf16x8 xb = *(const bf16x8*)(lds + XB + ((ks*6+nt)*4+kgl)*256 + lr*16);
                acc[nt] = MFMA(wf[ks], xb, acc[nt]);
            }
        // epilogue: + s*bq -> bf16 q-planes (K-style layout in V region)
        const float qs = 0.17677669529663687f;
        const int kg = (wv & 1)*2 + (kgl >> 1);
        float4 b4 = *(const float4*)(bq + wv*16 + kgl*4);
        #pragma unroll
        for (int nt = 0; nt < 6; nt++) {
            ushort4 o;
            o.x = to_bf16(acc[nt][0] + b4.x*qs);
            o.y = to_bf16(acc[nt][1] + b4.y*qs);
            o.z = to_bf16(acc[nt][2] + b4.z*qs);
            o.w = to_bf16(acc[nt][3] + b4.w*qs);
            *(ushort4*)(lds + VB + ((h*6+nt)*4+kg)*256 + lr*16 + (kgl&1)*8) = o;
        }
    }
    __syncthreads();                               // (2)

    // ---- write Xk planes; pull q frags to regs; prefetch Xv ----
    #pragma unroll
    for (int c = 0; c < 3; c++)
        *(uint4*)(lds + XB + saddr[c]) = pack8(pf[2*c], pf[2*c+1]);
    bf16x8 qf[3];
    #pragma unroll
    for (int j = 0; j < 3; j++)
        qf[j] = *(const bf16x8*)(lds + VB + ((h*6 + ib + j)*4 + kgl)*256 + lr*16);
    #pragma unroll
    for (int c = 0; c < 3; c++) {
        const float* p = Xv + xoff + srow[c] * D_ + skc[c] * 8;
        pf[2*c] = *(const float4*)p; pf[2*c+1] = *(const float4*)(p + 4);
    }
    __syncthreads();                               // (3)

    // ---- k^T GEMM -> K planes ----
    {
        const ushort* Wk = W + WSZ;
        bf16x8 wf[8];
        #pragma unroll
        for (int ks = 0; ks < 8; ks++)
            wf[ks] = *(const bf16x8*)(Wk + ((size_t)(ks*4+kgl)*256 + wv*16 + lr)*8);
        f32x4 acc[6];
        #pragma unroll
        for (int nt = 0; nt < 6; nt++) acc[nt] = (f32x4)0.f;
        #pragma unroll
        for (int ks = 0; ks < 8; ks++)
            #pragma unroll
            for (int nt = 0; nt < 6; nt++) {
                bf16x8 xb = *(const bf16x8*)(lds + XB + ((ks*6+nt)*4+kgl)*256 + lr*16);
                acc[nt] = MFMA(wf[ks], xb, acc[nt]);
            }
        const int kg = (wv & 1)*2 + (kgl >> 1);
        float4 b4 = *(const float4*)(bk + wv*16 + kgl*4);
        #pragma unroll
        for (int nt = 0; nt < 6; nt++) {
            ushort4 o;
            o.x = to_bf16(acc[nt][0] + b4.x);
            o.y = to_bf16(acc[nt][1] + b4.y);
            o.z = to_bf16(acc[nt][2] + b4.z);
            o.w = to_bf16(acc[nt][3] + b4.w);
            *(ushort4*)(lds + KB + ((h*6+nt)*4+kg)*256 + lr*16 + (kgl&1)*8) = o;
        }
    }
    __syncthreads();                               // (4)

    // ---- write Xv planes ----
    #pragma unroll
    for (int c = 0; c < 3; c++)
        *(uint4*)(lds + XB + saddr[c]) = pack8(pf[2*c], pf[2*c+1]);
    __syncthreads();                               // (5)

    // ---- v GEMM (normal): M = t, N = d (tile wv) -> V planes ----
    {
        const ushort* Wv = W + 2*WSZ;
        bf16x8 wf[8];
        #pragma unroll
        for (int ks = 0; ks < 8; ks++)
            wf[ks] = *(const bf16x8*)(Wv + ((size_t)(ks*4+kgl)*256 + wv*16 + lr)*8);
        f32x4 av[6];
        #pragma unroll
        for (int mt = 0; mt < 6; mt++) av[mt] = (f32x4)0.f;
        #pragma unroll
        for (int ks = 0; ks < 8; ks++)
            #pragma unroll
            for (int mt = 0; mt < 6; mt++) {
                bf16x8 xa = *(const bf16x8*)(lds + XB + ((ks*6+mt)*4+kgl)*256 + lr*16);
                av[mt] = MFMA(xa, wf[ks], av[mt]);
            }
        // epilogue: d-col tile wv -> head h, hd-half n2v; acc row t = mt*16+kgl*4+r
        const int n2v = wv & 1;
        const float bvv = bv[wv*16 + lr];
        #pragma unroll
        for (int mt = 0; mt < 6; mt++) {
            const int kvkg = mt*2 + (kgl >> 1);
            const int s2 = kvkg >> 2, kgv = kvkg & 3;
            ushort4 o;
            o.x = to_bf16(av[mt][0] + bvv);
            o.y = to_bf16(av[mt][1] + bvv);
            o.z = to_bf16(av[mt][2] + bvv);
            o.w = to_bf16(av[mt][3] + bvv);
            *(ushort4*)(lds + VB + (((h*3+s2)*2+n2v)*4+kgv)*256 + lr*16 + (kgl&1)*8) = o;
        }
    }
    __syncthreads();                               // (6)

    // ---- attention: head h, 3 q-row tiles; swapped QK^T, in-reg softmax,
    //      P via per-wave 3KB scratch (freed X region), PV ----
    f32x4 oacc[3][2];
    #pragma unroll
    for (int j = 0; j < 3; j++) { oacc[j][0] = (f32x4)0.f; oacc[j][1] = (f32x4)0.f; }
    {
        char* sw = lds + XB + wv * 3072;           // 12 planes x 256B
        #pragma unroll
        for (int j = 0; j < 3; j++) {
            f32x4 s[6];
            #pragma unroll
            for (int mt = 0; mt < 6; mt++) {
                bf16x8 kf = *(const bf16x8*)(lds + KB + ((h*6+mt)*4+kgl)*256 + lr*16);
                s[mt] = MFMA(kf, qf[j], (f32x4)0.f);   // rows kv, col q = lr
            }
            float mx = s[0][0];
            #pragma unroll
            for (int mt = 0; mt < 6; mt++)
                #pragma unroll
                for (int r = 0; r < 4; r++) mx = fmaxf(mx, s[mt][r]);
            mx = fmaxf(mx, __shfl_xor(mx, 16));
            mx = fmaxf(mx, __shfl_xor(mx, 32));
            float sum = 0.f;
            #pragma unroll
            for (int mt = 0; mt < 6; mt++)
                #pragma unroll
                for (int r = 0; r < 4; r++) {
                    float e = __expf(s[mt][r] - mx);
                    s[mt][r] = e; sum += e;
                }
            sum += __shfl_xor(sum, 16);
            sum += __shfl_xor(sum, 32);
            const float inv = 1.f / sum;
            #pragma unroll
            for (int mt = 0; mt < 6; mt++) {
                uint2 u2;
                u2.x = pack2(s[mt][0]*inv, s[mt][1]*inv);
                u2.y = pack2(s[mt][2]*inv, s[mt][3]*inv);
                *(uint2*)(sw + (mt*2 + (kgl>>1))*256 + lr*16 + (kgl&1)*8) = u2;
            }
            #pragma unroll
            for (int s2 = 0; s2 < 3; s2++) {
                bf16x8 pa = *(const bf16x8*)(sw + (s2*4+kgl)*256 + lr*16);
                #pragma unroll
                for (int n2 = 0; n2 < 2; n2++) {
                    bf16x8 vf = *(const bf16x8*)(lds + VB + (((h*3+s2)*2+n2)*4+kgl)*256 + lr*16);
                    oacc[j][n2] = MFMA(pa, vf, oacc[j][n2]);
                }
            }
        }
    }
    __syncthreads();                               // (7) scratch dead

    // ---- O -> O planes (X layout), bf16 ----
    #pragma unroll
    for (int j = 0; j < 3; j++)
        #pragma unroll
        for (int n2 = 0; n2 < 2; n2++) {
            const int dcol = h*32 + n2*16 + lr;
            const int kc   = dcol >> 3;            // 0..31
            const int irow = ib + j;
            char* base = lds + XB + (((kc>>2)*6 + irow)*4 + (kc&3))*256 + (dcol&7)*2;
            #pragma unroll
            for (int r = 0; r < 4; r++)
                *(ushort*)(base + (kgl*4+r)*16) = to_bf16(oacc[j][n2][r]);
        }
    __syncthreads();                               // (8)

    // ---- wo GEMM: M = t (O planes), N = d (tile wv) -> d_out fp32 + bo ----
    {
        const ushort* Wo = W + 3*WSZ;
        bf16x8 wf[8];
        #pragma unroll
        for (int ks = 0; ks < 8; ks++)
            wf[ks] = *(const bf16x8*)(Wo + ((size_t)(ks*4+kgl)*256 + wv*16 + lr)*8);
        f32x4 a2[6];
        #pragma unroll
        for (int mt = 0; mt < 6; mt++) a2[mt] = (f32x4)0.f;
        #pragma unroll
        for (int ks = 0; ks < 8; ks++)
            #pragma unroll
            for (int mt = 0; mt < 6; mt++) {
                bf16x8 oa = *(const bf16x8*)(lds + XB + ((ks*6+mt)*4+kgl)*256 + lr*16);
                a2[mt] = MFMA(oa, wf[ks], a2[mt]);
            }
        const float bod = bo[wv*16 + lr];
        #pragma unroll
        for (int mt = 0; mt < 6; mt++)
            #pragma unroll
            for (int r = 0; r < 4; r++) {
                const int t = mt*16 + kgl*4 + r;
                out[((size_t)(bn*T_ + t))*D_ + wv*16 + lr] = a2[mt][r] + bod;
            }
    }
}

// ---------------------------------------------------------------------------
extern "C" void kernel_launch(void* const* d_in, const int* in_sizes, int n_in,
                              void* d_out, int out_size, void* d_ws, size_t ws_size,
                              hipStream_t stream)
{
    const float* query = (const float*)d_in[0];
    const float* key   = (const float*)d_in[1];
    const float* value = (const float*)d_in[2];
    // d_in[3..5]: pattern_matrix, Wp, bp -- mathematically a no-op (mask == 1)
    const float* Wq = (const float*)d_in[6];
    const float* bq = (const float*)d_in[7];
    const float* Wk = (const float*)d_in[8];
    const float* bk = (const float*)d_in[9];
    const float* Wv = (const float*)d_in[10];
    const float* bv = (const float*)d_in[11];
    const float* Wo = (const float*)d_in[12];
    const float* bo = (const float*)d_in[13];

    float*  out = (float*)d_out;
    ushort* whi = (ushort*)d_ws;   // 4 matrices, chunked bf16: 512 KB

    splitw_kernel<<<dim3(128), 256, 0, stream>>>(Wq, Wk, Wv, Wo, whi);
    mega_kernel<<<dim3(BN_), 1024, 0, stream>>>(
        query, key, value, whi, bq, bk, bv, bo, out);
}